// Round 24
// baseline (75.285 us; speedup 1.0000x reference)
//
#include <hip/hip_runtime.h>
#include <cfloat>

// Problem constants (fixed by setup_inputs)
#define C_DIM   256
#define HW      1024
#define N_ROWS  32768
#define K_CODES 1024
#define ROWS    64            // rows per workgroup
#define NSUPER  16            // 16 superchunks x 64 codes
#define SUPER_BYTES 32768     // 64 codes * 256 * 2B fp16
#define LISTCAP 128           // per-wave candidate cap
#define DELTA   0.008f
#define CMASK   0xFFFFFFF0u   // clear low 4 mantissa bits for superchunk-id packing
#define ZSTRIDE 260           // zt padded stride (floats)

#define OUT_ELEMS 8388608
#define LOSS_OFF  8388608
#define IDX_OFF   8388611

typedef _Float16 half8 __attribute__((ext_vector_type(8)));
typedef _Float16 f16x4 __attribute__((ext_vector_type(4)));
typedef float    f32x4 __attribute__((ext_vector_type(4)));

#define AS1 __attribute__((address_space(1)))
#define AS3 __attribute__((address_space(3)))

// ---- vq_sweep dynamic LDS layout (bytes) ----
// zt [64][260] f32 (66560B) prologue-only; ebuf (2 x 32768 = 65536B) aliases it.
#define OFF_EBUF  0
#define OFF_EN    66560                // 1024*4 -> 70656
#define OFF_S32   70656                // 64*4 -> 70912
#define OFF_M1W   70912                // 4*64*4 -> 71936
#define OFF_THR   71936                // 64*4 -> 72192
#define OFF_LCNT  72192                // 8*4 -> 72224, pad
#define SMEM_A    72448                // x2 = 144896 <= 163840 -> 2 blocks/CU

#define QT_STRIDE 258

// ---- workspace layout (bytes) ----
#define WS_CB16   0                    // 524288
#define WS_T2     524288               // 131072
#define WS_EN     655360               // 4096
#define WS_S32    659456               // 512*64*4 = 131072
#define WS_LCNT   790528               // 512*8*4  = 16384
#define WS_LMETA  806912               // 512*8*128*4 = 2097152  (total ~2.9MB)

// min across the 16-lane row group (lanes sharing lane>>4)
#define DPP_MIN(x, ctrl) fminf((x), __int_as_float(__builtin_amdgcn_update_dpp(0, __float_as_int(x), (ctrl), 0xf, 0xf, true)))

// Kernel 1: codebook prep — fp32 norms (fp64-accurate) + fp16 copy, kk-major layout.
__global__ void prep_kernel(const float* __restrict__ cb, float* __restrict__ enorm,
                            char* __restrict__ cb16) {
    int k = blockIdx.x * 4 + (threadIdx.x >> 6);
    int lane = threadIdx.x & 63;
    int c0 = lane * 4;
    float4 v = *(const float4*)(cb + k * C_DIM + c0);
    double s = (double)v.x * v.x + (double)v.y * v.y + (double)v.z * v.z + (double)v.w * v.w;
    #pragma unroll
    for (int m = 1; m < 64; m <<= 1) s += __shfl_xor(s, m, 64);
    if (lane == 0) enorm[k] = (float)s;
    f16x4 h;
    h[0] = (_Float16)v.x; h[1] = (_Float16)v.y; h[2] = (_Float16)v.z; h[3] = (_Float16)v.w;
    int dst = ((k >> 4) << 13) + ((c0 >> 5) << 10) + (((c0 >> 3) & 3) << 8)
            + ((k & 15) << 4) + ((c0 & 7) << 1);
    *(f16x4*)(cb16 + dst) = h;
}

// Kernel 2a: prologue + fp16-MFMA sweep + thr + candidate push -> workspace.
// (R23 structure: 8 waves = 2 row-halves x 4 code-quarters; 64-code superchunks,
//  2x32KB double-buffer; kk-major ds_reads; packed top-2.)
__global__ __launch_bounds__(512, 4) void vq_sweep(
    const float* __restrict__ x, const float* __restrict__ enorm_g,
    const char* __restrict__ cb16, float* __restrict__ S32_g,
    int* __restrict__ lcnt_g, unsigned int* __restrict__ lmeta_g)
{
    extern __shared__ char smem[];
    float* zt      = (float*)(smem + OFF_EBUF);
    char*  ebuf    = smem + OFF_EBUF;
    float* en_lds  = (float*)(smem + OFF_EN);
    float* S32     = (float*)(smem + OFF_S32);
    float* m1w     = (float*)(smem + OFF_M1W);
    float* thr     = (float*)(smem + OFF_THR);
    int*   lcnt    = (int*)(smem + OFF_LCNT);

    const int t    = threadIdx.x;
    const int lane = t & 63;
    const int wv   = t >> 6;           // 0..7
    const int wr   = wv >> 2;          // row half
    const int wq   = wv & 3;           // code quarter
    const int l15  = lane & 15;
    const int l4   = lane >> 4;
    const int blk  = blockIdx.x;
    const int row0 = blk * ROWS;
    const int b    = row0 >> 10;
    const int hw0  = row0 & 1023;
    const float* xb = x + b * (C_DIM * HW) + hw0;

    const int qofs = wv * 4096;

    // ---- phase 1: stage z tile + enorm ----
    {
        int g   = t & 15;
        int cb4 = t >> 4;
        for (int cc = cb4 * 4; cc < C_DIM; cc += 128) {
            float4 v0 = *(const float4*)(xb + (cc + 0) * HW + g * 4);
            float4 v1 = *(const float4*)(xb + (cc + 1) * HW + g * 4);
            float4 v2 = *(const float4*)(xb + (cc + 2) * HW + g * 4);
            float4 v3 = *(const float4*)(xb + (cc + 3) * HW + g * 4);
            *(float4*)&zt[(g * 4 + 0) * ZSTRIDE + cc] = make_float4(v0.x, v1.x, v2.x, v3.x);
            *(float4*)&zt[(g * 4 + 1) * ZSTRIDE + cc] = make_float4(v0.y, v1.y, v2.y, v3.y);
            *(float4*)&zt[(g * 4 + 2) * ZSTRIDE + cc] = make_float4(v0.z, v1.z, v2.z, v3.z);
            *(float4*)&zt[(g * 4 + 3) * ZSTRIDE + cc] = make_float4(v0.w, v1.w, v2.w, v3.w);
        }
        if (t < 256) *(float4*)&en_lds[t * 4] = *(const float4*)(enorm_g + t * 4);
        if (t < 8) lcnt[t] = 0;
    }
    __syncthreads();

    // ---- phase 2: fp64 S32 + A fragments ----
    if (t < 256) {
        int r = t >> 2, seg = t & 3;
        const float* zr = &zt[r * ZSTRIDE + seg * 64];
        double s = 0.0;
        for (int c = 0; c < 64; c += 4) {
            float4 v = *(const float4*)(zr + c);
            s = fma((double)v.x, (double)v.x, s);
            s = fma((double)v.y, (double)v.y, s);
            s = fma((double)v.z, (double)v.z, s);
            s = fma((double)v.w, (double)v.w, s);
        }
        s += __shfl_xor(s, 1, 64);
        s += __shfl_xor(s, 2, 64);
        if (seg == 0) { S32[r] = (float)s; S32_g[blk * 64 + r] = (float)s; }
    }

    half8 af[2][8];
    #pragma unroll
    for (int rt = 0; rt < 2; rt++) {
        int row = wr * 32 + rt * 16 + l15;
        #pragma unroll
        for (int kk = 0; kk < 8; kk++) {
            int c0 = kk * 32 + l4 * 8;
            float4 a  = *(const float4*)&zt[row * ZSTRIDE + c0];
            float4 a2 = *(const float4*)&zt[row * ZSTRIDE + c0 + 4];
            half8 h;
            h[0] = (_Float16)(-2.0f * a.x);  h[1] = (_Float16)(-2.0f * a.y);
            h[2] = (_Float16)(-2.0f * a.z);  h[3] = (_Float16)(-2.0f * a.w);
            h[4] = (_Float16)(-2.0f * a2.x); h[5] = (_Float16)(-2.0f * a2.y);
            h[6] = (_Float16)(-2.0f * a2.z); h[7] = (_Float16)(-2.0f * a2.w);
            af[rt][kk] = h;
        }
    }
    __syncthreads();   // zt dead; ebuf may overwrite (drains vmcnt too)

    // ---- issue eighth of superchunk 0 ----
    #pragma unroll
    for (int i = 0; i < 4; i++) {
        __builtin_amdgcn_global_load_lds((const AS1 unsigned int*)(cb16 + qofs + i * 1024 + lane * 16),
                                         (AS3 unsigned int*)(ebuf + qofs + i * 1024), 16, 0, 0);
    }

    const int bbase  = (wq << 13) + (l4 << 8) + (l15 << 4);
    const int enbase = wq * 16 + l15;

    float u1[2][4], u2[2][4];
    #pragma unroll
    for (int rt = 0; rt < 2; rt++)
        #pragma unroll
        for (int r2 = 0; r2 < 4; r2++) { u1[rt][r2] = FLT_MAX; u2[rt][r2] = FLT_MAX; }

    for (int sc = 0; sc < NSUPER; sc++) {
        asm volatile("s_waitcnt vmcnt(0)" ::: "memory");
        __builtin_amdgcn_sched_barrier(0);
        __builtin_amdgcn_s_barrier();
        __builtin_amdgcn_sched_barrier(0);

        const char* ebc = ebuf + (sc & 1) * SUPER_BYTES;

        if (sc + 1 < NSUPER) {
            const char* src = cb16 + (sc + 1) * SUPER_BYTES + qofs;
            char* dst = ebuf + ((sc + 1) & 1) * SUPER_BYTES + qofs;
            #pragma unroll
            for (int i = 0; i < 4; i++) {
                __builtin_amdgcn_global_load_lds((const AS1 unsigned int*)(src + i * 1024 + lane * 16),
                                                 (AS3 unsigned int*)(dst + i * 1024), 16, 0, 0);
            }
        }

        const float en = en_lds[enbase + sc * 64];
        f32x4 acc0 = {en, en, en, en};
        f32x4 acc1 = {en, en, en, en};
        {
            half8 bf[4];
            #pragma unroll
            for (int kk = 0; kk < 4; kk++)
                bf[kk] = *(const half8*)(ebc + bbase + (kk << 10));
            #pragma unroll
            for (int kk = 0; kk < 4; kk++) {
                acc0 = __builtin_amdgcn_mfma_f32_16x16x32_f16(af[0][kk], bf[kk], acc0, 0, 0, 0);
                acc1 = __builtin_amdgcn_mfma_f32_16x16x32_f16(af[1][kk], bf[kk], acc1, 0, 0, 0);
            }
        }
        {
            half8 bf[4];
            #pragma unroll
            for (int kk = 0; kk < 4; kk++)
                bf[kk] = *(const half8*)(ebc + bbase + ((kk + 4) << 10));
            #pragma unroll
            for (int kk = 0; kk < 4; kk++) {
                acc0 = __builtin_amdgcn_mfma_f32_16x16x32_f16(af[0][kk + 4], bf[kk], acc0, 0, 0, 0);
                acc1 = __builtin_amdgcn_mfma_f32_16x16x32_f16(af[1][kk + 4], bf[kk], acc1, 0, 0, 0);
            }
        }

        #pragma unroll
        for (int r2 = 0; r2 < 4; r2++) {
            float a0 = __uint_as_float((__float_as_uint(acc0[r2]) & CMASK) | (unsigned)sc);
            u2[0][r2] = __builtin_amdgcn_fmed3f(a0, u1[0][r2], u2[0][r2]);
            u1[0][r2] = fminf(u1[0][r2], a0);
            float a1 = __uint_as_float((__float_as_uint(acc1[r2]) & CMASK) | (unsigned)sc);
            u2[1][r2] = __builtin_amdgcn_fmed3f(a1, u1[1][r2], u2[1][r2]);
            u1[1][r2] = fminf(u1[1][r2], a1);
        }
    }

    // ---- reduce -> thr ----
    #pragma unroll
    for (int rt = 0; rt < 2; rt++) {
        #pragma unroll
        for (int r2 = 0; r2 < 4; r2++) {
            float m = u1[rt][r2];
            m = DPP_MIN(m, 0xB1);
            m = DPP_MIN(m, 0x4E);
            m = DPP_MIN(m, 0x141);
            m = DPP_MIN(m, 0x140);
            if (l15 == 0) m1w[wq * 64 + wr * 32 + rt * 16 + l4 * 4 + r2] = m;
        }
    }
    __syncthreads();
    if (t < 64)
        thr[t] = fminf(fminf(m1w[t], m1w[64 + t]), fminf(m1w[128 + t], m1w[192 + t])) + DELTA;
    __syncthreads();

    // ---- push candidates to workspace ----
    unsigned int* lmb = lmeta_g + blk * (8 * LISTCAP) + wv * LISTCAP;
    #pragma unroll
    for (int rt = 0; rt < 2; rt++) {
        #pragma unroll
        for (int r2 = 0; r2 < 4; r2++) {
            int row_l = wr * 32 + rt * 16 + l4 * 4 + r2;
            float tr = thr[row_l];
            if (u1[rt][r2] < tr) {
                int sc1 = (int)(__float_as_uint(u1[rt][r2]) & 15u);
                int code = sc1 * 64 + wq * 16 + l15;
                int slot = atomicAdd(&lcnt[wv], 1);
                if (slot < LISTCAP) lmb[slot] = ((unsigned)row_l << 16) | (unsigned)code;
            }
            if (u2[rt][r2] < tr) {
                int sc2 = (int)(__float_as_uint(u2[rt][r2]) & 15u);
                int code = sc2 * 64 + wq * 16 + l15;
                int slot = atomicAdd(&lcnt[wv], 1);
                if (slot < LISTCAP) lmb[slot] = ((unsigned)row_l << 16) | (unsigned)code;
            }
        }
    }
    __syncthreads();
    if (t < 8) {
        int n = lcnt[t]; if (n > LISTCAP) n = LISTCAP;
        lcnt_g[blk * 8 + t] = n;
    }
}

// Kernel 2b: rescore survivors + idx/t2 + quantized output (256 threads, small LDS).
__global__ __launch_bounds__(256) void vq_finish(
    const float* __restrict__ x, const float* __restrict__ cb,
    const float* __restrict__ enorm_g, const float* __restrict__ S32_g,
    const int* __restrict__ lcnt_g, const unsigned int* __restrict__ lmeta_g,
    float* __restrict__ out, float* __restrict__ idx_out, float* __restrict__ t2_out)
{
    __shared__ __align__(16) float qt[32 * QT_STRIDE];
    __shared__ float S32l[64];
    __shared__ unsigned long long res[64];
    __shared__ int fidx[64];

    const int t    = threadIdx.x;
    const int grp  = t >> 4;           // 0..15: candidate-entry group
    const int l15  = t & 15;
    const int blk  = blockIdx.x;
    const int row0 = blk * ROWS;
    const int b    = row0 >> 10;
    const int hw0  = row0 & 1023;
    const float* xb = x + b * (C_DIM * HW) + hw0;

    if (t < 64) { S32l[t] = S32_g[blk * 64 + t]; res[t] = ~0ull; }
    __syncthreads();

    // ---- rescore: 8 per-wave segments from the sweep kernel ----
    const unsigned int* lmb = lmeta_g + blk * (8 * LISTCAP);
    for (int wseg = 0; wseg < 8; wseg++) {
        int n = lcnt_g[blk * 8 + wseg];
        for (int base = 0; base < n; base += 16) {
            int it = base + grp;
            if (it < n) {
                unsigned meta = lmb[wseg * LISTCAP + it];
                int row  = (int)(meta >> 16);
                int code = (int)(meta & 1023u);
                const float* xr = xb + row;
                const float* er = cb + code * C_DIM;
                double acc = 0.0;
                #pragma unroll
                for (int s2 = 0; s2 < 16; s2++) {
                    int c = l15 + 16 * s2;
                    acc = fma((double)xr[(size_t)c * HW], (double)er[c], acc);
                }
                acc += __shfl_xor(acc, 1, 64);
                acc += __shfl_xor(acc, 2, 64);
                acc += __shfl_xor(acc, 4, 64);
                acc += __shfl_xor(acc, 8, 64);
                if (l15 == 0) {
                    float Mf = (float)acc;
                    float t2 = __fadd_rn(__fsub_rn(S32l[row], __fmul_rn(2.0f, Mf)), enorm_g[code]);
                    unsigned long long pk =
                        ((unsigned long long)__float_as_uint(t2) << 32) | (unsigned long long)(unsigned)code;
                    atomicMin(&res[row], pk);
                }
            }
        }
    }
    __syncthreads();

    if (t < 64) {
        unsigned long long v = res[t];
        int code = (int)(v & 1023u);
        fidx[t] = code;
        idx_out[row0 + t] = (float)code;
        t2_out[row0 + t] = __uint_as_float((unsigned)(v >> 32));
    }

    // ---- quantized output via LDS bounce ----
    float* ob = out + b * (C_DIM * HW) + hw0;
    #pragma unroll
    for (int half = 0; half < 2; half++) {
        __syncthreads();
        for (int idx = t; idx < 32 * 64; idx += 256) {
            int r  = idx >> 6;
            int c4 = idx & 63;
            const float* er = cb + fidx[half * 32 + r] * C_DIM;
            *(float4*)&qt[r * QT_STRIDE + c4 * 4] = *(const float4*)(er + c4 * 4);
        }
        __syncthreads();
        int rr = t & 31;
        int cg = t >> 5;
        for (int cc = cg; cc < C_DIM; cc += 8) {
            ob[cc * HW + half * 32 + rr] = qt[rr * QT_STRIDE + cc];
        }
    }
}

// Kernel 3: deterministic loss reduction over per-row t2
__global__ void loss_kernel(const float* __restrict__ t2min, float* __restrict__ losses) {
    __shared__ double sh[256];
    int t = threadIdx.x;
    double a = 0.0;
    const int per = N_ROWS / 256;
    for (int i = t * per; i < t * per + per; i++) a += (double)t2min[i];
    sh[t] = a;
    __syncthreads();
    for (int s = 128; s > 0; s >>= 1) {
        if (t < s) sh[t] += sh[t + s];
        __syncthreads();
    }
    if (t == 0) {
        double M = sh[0] / (double)OUT_ELEMS;
        losses[0] = (float)(1.25 * M);   // quantizer_loss
        losses[1] = (float)(0.25 * M);   // e_latent_loss
        losses[2] = (float)(M);          // q_latent_loss
    }
}

extern "C" void kernel_launch(void* const* d_in, const int* in_sizes, int n_in,
                              void* d_out, int out_size, void* d_ws, size_t ws_size,
                              hipStream_t stream) {
    const float* x  = (const float*)d_in[0];
    const float* cb = (const float*)d_in[1];
    float* out     = (float*)d_out;
    float* losses  = out + LOSS_OFF;
    float* idx_out = out + IDX_OFF;

    char* ws = (char*)d_ws;
    char*  cb16     = ws + WS_CB16;
    float* t2ws     = (float*)(ws + WS_T2);
    float* enorm_ws = (float*)(ws + WS_EN);
    float* S32_g    = (float*)(ws + WS_S32);
    int*   lcnt_g   = (int*)(ws + WS_LCNT);
    unsigned int* lmeta_g = (unsigned int*)(ws + WS_LMETA);

    hipFuncSetAttribute(reinterpret_cast<const void*>(vq_sweep),
                        hipFuncAttributeMaxDynamicSharedMemorySize, SMEM_A);

    prep_kernel<<<K_CODES / 4, 256, 0, stream>>>(cb, enorm_ws, cb16);
    vq_sweep<<<N_ROWS / ROWS, 512, SMEM_A, stream>>>(x, enorm_ws, cb16, S32_g, lcnt_g, lmeta_g);
    vq_finish<<<N_ROWS / ROWS, 256, 0, stream>>>(x, cb, enorm_ws, S32_g, lcnt_g, lmeta_g,
                                                 out, idx_out, t2ws);
    loss_kernel<<<1, 256, 0, stream>>>(t2ws, losses);
}